// Round 9
// baseline (87.960 us; speedup 1.0000x reference)
//
#include <hip/hip_runtime.h>
#include <hip/hip_bf16.h>

typedef __bf16 bf16x8 __attribute__((ext_vector_type(8)));
typedef float f32x4 __attribute__((ext_vector_type(4)));

// Pre-kernel: clusters (128x512 f32) -> bf16 in ws, plus fp32 c2[128].
__global__ __launch_bounds__(64)
void prep_clusters(const float* __restrict__ c, __bf16* __restrict__ cb,
                   float* __restrict__ c2)
{
    const int row = blockIdx.x;     // 0..127
    const int l = threadIdx.x;      // 0..63
    const float* p = c + row * 512 + l * 8;
    f32x4 u0 = *(const f32x4*)p;
    f32x4 u1 = *(const f32x4*)(p + 4);
    bf16x8 v;
    float s = 0.f;
#pragma unroll
    for (int j = 0; j < 4; ++j) {
        v[j]     = (__bf16)u0[j];
        v[4 + j] = (__bf16)u1[j];
        s += u0[j] * u0[j] + u1[j] * u1[j];
    }
    *(bf16x8*)(cb + row * 512 + l * 8) = v;
#pragma unroll
    for (int off = 32; off >= 1; off >>= 1) s += __shfl_xor(s, off);
    if (l == 0) c2[row] = s;
}

// 2-DEEP REGISTER PREFETCH: at top of pass p we issue loads for pass p+2
// (GI) while pass p+1's loads (GR) are still in flight — per-block reads are
// outstanding ~continuously, lifting chip-wide in-flight bytes from ~3 MB
// (burst-then-idle, = the 3.7 TB/s plateau of R3..R8) to ~16+ MB >> the
// 5.7 MB BW*latency product, so the HBM controller never starves.
// LDS is a true double buffer (no WAR wait before ds_write). Epilogue stores
// are issued BEFORE the counted vmcnt(16) so the count uniformly drains
// exactly GR (8 GI + 8 stores remain in flight). B persistent in registers.
__global__ __launch_bounds__(256, 2)
void cluster_q_mfma(const float* __restrict__ x,
                    const __bf16* __restrict__ cb,
                    const float* __restrict__ c2,
                    float* __restrict__ out)
{
    __shared__ float lds[2][16 * 512];   // 2 x 32 KB tiles (16 rows x 512)
    __shared__ float rsx[16][4];         // [row][wave] partial row sums

    const int tid = threadIdx.x;
    const int l = tid & 63;
    const int w = tid >> 6;         // wave 0..3: owns cols w*32 .. w*32+31
    const int m = l & 15;           // fragment row (A) / col (B)
    const int g = l >> 4;           // k-group 0..3
    const long brow = (long)blockIdx.x * 256;

    float c2v[2];
#pragma unroll
    for (int nb = 0; nb < 2; ++nb) c2v[nb] = c2[w * 32 + nb * 16 + m];

    // Persistent B: cols w*32+nb*16+m, all 512 k. 32 x b128 loads, 128 VGPRs.
    bf16x8 bR[2][16];
#pragma unroll
    for (int nb = 0; nb < 2; ++nb)
#pragma unroll
        for (int ks = 0; ks < 16; ++ks)
            bR[nb][ks] = *(const bf16x8*)(
                cb + (w * 32 + nb * 16 + m) * 512 + ks * 32 + g * 8);

    // Global-load geometry: instr i_ covers rows P*16 + i_*2 + (tid>>7);
    // lane chunk = tid&127 (each instr = 4 KB fully contiguous).
    const int t7 = tid >> 7;
    const int ck = tid & 127;
    const float* gbase = x + (brow + t7) * 512 + ck * 4;

    // LDS read bases (bytes): row m, chunk (ks*8 + (2g+h)) ^ lo3 (m&7).
    const int rbo0 = m * 2048 + (((2 * g)     ^ (m & 7)) * 16);
    const int rbo1 = m * 2048 + (((2 * g + 1) ^ (m & 7)) * 16);

    f32x4 GA[8], GB[8];

#define SB __builtin_amdgcn_sched_barrier(0)
#define GLOAD(G, P)                                                       \
    { _Pragma("unroll")                                                   \
      for (int i_ = 0; i_ < 8; ++i_)                                      \
          G[i_] = *(const f32x4*)(gbase + (long)((P) * 16 + i_ * 2) * 512); }
// ds_write: row_l = i_*2 + t7; chunk position = ck with lo-3 XOR (row_l & 7).
#define DSWRITE(BUF, G)                                                   \
    { _Pragma("unroll")                                                   \
      for (int i_ = 0; i_ < 8; ++i_) {                                    \
          const int row_l = i_ * 2 + t7;                                  \
          *(f32x4*)(&lds[BUF][row_l * 512 + (ck ^ (row_l & 7)) * 4]) = G[i_]; \
      } }

    // Prologue: tile 0 -> LDS buf0; tile 1 loads left in flight in GA.
    GLOAD(GA, 0);
    asm volatile("s_waitcnt vmcnt(0)" ::: "memory");
    DSWRITE(0, GA);
    GLOAD(GA, 1);
    asm volatile("s_waitcnt lgkmcnt(0)" ::: "memory");
    __builtin_amdgcn_s_barrier();

#define PASS_BODY(P, BUF, GR, GI)                                         \
    {                                                                     \
        const int Pn = ((P) + 2 < 16) ? (P) + 2 : 15;                     \
        GLOAD(GI, Pn);            /* always issue: keeps vmcnt uniform */ \
        SB;                                                               \
        f32x4 acc[2] = {f32x4{0.f,0.f,0.f,0.f}, f32x4{0.f,0.f,0.f,0.f}};  \
        float x2p = 0.f;                                                  \
        const char* L = (const char*)&lds[BUF][0];                        \
        _Pragma("unroll")                                                 \
        for (int ks = 0; ks < 16; ++ks) {                                 \
            f32x4 u0 = *(const f32x4*)(L + rbo0 + ks * 128);              \
            f32x4 u1 = *(const f32x4*)(L + rbo1 + ks * 128);              \
            bf16x8 aF;                                                    \
            _Pragma("unroll")                                             \
            for (int j = 0; j < 4; ++j) {                                 \
                aF[j]     = (__bf16)u0[j];                                \
                aF[4 + j] = (__bf16)u1[j];                                \
                x2p += u0[j] * u0[j] + u1[j] * u1[j];                     \
            }                                                             \
            acc[0] = __builtin_amdgcn_mfma_f32_16x16x32_bf16(aF, bR[0][ks], acc[0], 0, 0, 0); \
            acc[1] = __builtin_amdgcn_mfma_f32_16x16x32_bf16(aF, bR[1][ks], acc[1], 0, 0, 0); \
        }                                                                 \
        x2p += __shfl_xor(x2p, 16);                                       \
        x2p += __shfl_xor(x2p, 32);                                       \
        float x2r[4], rs[4];                                              \
        _Pragma("unroll")                                                 \
        for (int r = 0; r < 4; ++r) {                                     \
            x2r[r] = __shfl(x2p, g * 4 + r);                              \
            rs[r] = 0.f;                                                  \
        }                                                                 \
        _Pragma("unroll")                                                 \
        for (int nb = 0; nb < 2; ++nb)                                    \
            _Pragma("unroll")                                             \
            for (int r = 0; r < 4; ++r) {                                 \
                float d2 = fmaxf(x2r[r] + c2v[nb] - 2.f * acc[nb][r], 0.f); \
                float qv = __builtin_amdgcn_rcpf(1.f + d2);               \
                acc[nb][r] = qv;                                          \
                rs[r] += qv;                                              \
            }                                                             \
        _Pragma("unroll")                                                 \
        for (int r = 0; r < 4; ++r) {                                     \
            rs[r] += __shfl_xor(rs[r], 1);                                \
            rs[r] += __shfl_xor(rs[r], 2);                                \
            rs[r] += __shfl_xor(rs[r], 4);                                \
            rs[r] += __shfl_xor(rs[r], 8);                                \
        }                                                                 \
        if (m == 0) {                                                     \
            _Pragma("unroll")                                             \
            for (int r = 0; r < 4; ++r) rsx[g * 4 + r][w] = rs[r];        \
        }                                                                 \
        asm volatile("s_waitcnt lgkmcnt(0)" ::: "memory");                \
        __builtin_amdgcn_s_barrier();   /* A: rsx ready */                \
        float inv[4];                                                     \
        _Pragma("unroll")                                                 \
        for (int r = 0; r < 4; ++r) {                                     \
            f32x4 v = *(const f32x4*)&rsx[g * 4 + r][0];                  \
            inv[r] = __builtin_amdgcn_rcpf(v[0] + v[1] + v[2] + v[3]);    \
        }                                                                 \
        const long orow = brow + (P) * 16 + g * 4;                        \
        _Pragma("unroll")                                                 \
        for (int r = 0; r < 4; ++r)                                       \
            _Pragma("unroll")                                             \
            for (int nb = 0; nb < 2; ++nb)                                \
                out[(orow + r) * 128 + w * 32 + nb * 16 + m] =            \
                    acc[nb][r] * inv[r];                                  \
        SB;                                                               \
        if ((P) < 15) {                                                   \
            asm volatile("s_waitcnt vmcnt(16)" ::: "memory"); /* drain GR */ \
            SB;                                                           \
            DSWRITE((BUF) ^ 1, GR);                                       \
            asm volatile("s_waitcnt lgkmcnt(0)" ::: "memory");            \
            __builtin_amdgcn_s_barrier();   /* B: next tile visible */    \
            SB;                                                           \
        }                                                                 \
    }

#pragma unroll 1
    for (int pp = 0; pp < 8; ++pp) {
        PASS_BODY(2 * pp,     0, GA, GB);
        PASS_BODY(2 * pp + 1, 1, GB, GA);
    }
#undef PASS_BODY
#undef GLOAD
#undef DSWRITE
#undef SB
}

extern "C" void kernel_launch(void* const* d_in, const int* in_sizes, int n_in,
                              void* d_out, int out_size, void* d_ws, size_t ws_size,
                              hipStream_t stream)
{
    const float* x = (const float*)d_in[0];
    const float* c = (const float*)d_in[1];
    float* out = (float*)d_out;

    float*  c2ws = (float*)d_ws;                        // 128 floats
    __bf16* cbws = (__bf16*)((char*)d_ws + 1024);       // 128x512 bf16 = 128 KB

    hipLaunchKernelGGL(prep_clusters, dim3(128), dim3(64), 0, stream, c, cbws, c2ws);

    const int N = in_sizes[0] / 512;                    // 131072 rows
    dim3 grid(N / 256), block(256);                     // 512 blocks = 2/CU
    hipLaunchKernelGGL(cluster_q_mfma, grid, block, 0, stream, x, cbws, c2ws, out);
}